// Round 14
// baseline (1003.249 us; speedup 1.0000x reference)
//
#include <hip/hip_runtime.h>
#include <hip/hip_bf16.h>
#include <cstdint>

// TGAT fused pipeline for MI355X — round 13: dst-range bucketing, zero global
// atomics.
//   pass A: per-bucket edge counts (LDS hist -> global)
//   pass B: exclusive scan (1 block) -> rowptr + cursor
//   pass C: scatter 8B payload {src, rel_f16, dstlow} into bucket regions
//           (block-staged: per-chunk LDS bucketing -> contiguous runs)
//   k1/k2 : unchanged (MFMA lin / MFMA enc+proj), skipb f32
//   k3b   : one block per bucket — q in LDS, kv gathered (bf16 quads),
//           MFMA edge features + attention, **fp32 LDS aggregation**,
//           fused epilogue (skip + @Wout + log_softmax), 8B/node write.
// Bucket width 128 (dst>>7); B = ceil(n/128) = 782 for n=100k (static LDS
// arrays sized 784; valid for n <= 100352).

#define FIN 172
#define INV_SQRT_C 0.25f
#define CHUNK 8192

typedef _Float16 f16x8 __attribute__((ext_vector_type(8)));
typedef float f32x4 __attribute__((ext_vector_type(4)));

__device__ __forceinline__ uint32_t cvt_pk_bf16(float lo, float hi) {
    uint32_t r;
    asm("v_cvt_pk_bf16_f32 %0, %1, %2" : "=v"(r) : "v"(lo), "v"(hi));
    return r;
}
__device__ __forceinline__ float bflo(uint32_t u) {
    union { uint32_t i; float f; } x; x.i = u << 16; return x.f;
}
__device__ __forceinline__ float bfhi(uint32_t u) {
    union { uint32_t i; float f; } x; x.i = u & 0xFFFF0000u; return x.f;
}

// ---------------------------------------------------------------------------
// k1 (MFMA): h1pre = x @ Wlin + blin.  (r12 verbatim)
// ---------------------------------------------------------------------------
__global__ __launch_bounds__(256) void k1_lin(
    const float* __restrict__ x, const float* __restrict__ Wlin,
    const float* __restrict__ blin, float* __restrict__ h1pre, int n)
{
    const int lane = threadIdx.x & 63;
    const int g = lane >> 4, m = lane & 15;

    f16x8 Bf[6][2];
    #pragma unroll
    for (int s = 0; s < 6; ++s) {
        #pragma unroll
        for (int i = 0; i < 8; ++i) {
            const int k = s * 32 + g * 8 + i;
            Bf[s][0][i] = (_Float16)((k < FIN) ? Wlin[k * 32 + m] : 0.f);
            Bf[s][1][i] = (_Float16)((k < FIN) ? Wlin[k * 32 + 16 + m] : 0.f);
        }
    }
    const float b0 = blin[m], b1 = blin[16 + m];

    const int wid = blockIdx.x * 4 + (threadIdx.x >> 6);
    const int nW  = gridDim.x * 4;
    const int nChunks = (n + 15) / 16;

    for (int c = wid; c < nChunks; c += nW) {
        const int row = c * 16 + m;
        const bool rv = row < n;
        const float* xr = x + (size_t)row * FIN;

        f32x4 acc0 = {0.f, 0.f, 0.f, 0.f};
        f32x4 acc1 = {0.f, 0.f, 0.f, 0.f};
        #pragma unroll
        for (int s = 0; s < 6; ++s) {
            f16x8 A;
            #pragma unroll
            for (int i = 0; i < 8; ++i) {
                const int k = s * 32 + g * 8 + i;
                A[i] = (_Float16)((rv && k < FIN) ? xr[k] : 0.f);
            }
            acc0 = __builtin_amdgcn_mfma_f32_16x16x32_f16(A, Bf[s][0], acc0, 0, 0, 0);
            acc1 = __builtin_amdgcn_mfma_f32_16x16x32_f16(A, Bf[s][1], acc1, 0, 0, 0);
        }
        #pragma unroll
        for (int r = 0; r < 4; ++r) {
            const int node = c * 16 + 4 * g + r;
            if (node < n) {
                h1pre[(size_t)node * 32 + m]      = acc0[r] + b0;
                h1pre[(size_t)node * 32 + 16 + m] = acc1[r] + b1;
            }
        }
    }
}

// ---------------------------------------------------------------------------
template <int K, int O>
__device__ __forceinline__ void matvecKO(const float* __restrict__ v,
                                         const float* __restrict__ W,
                                         const float* __restrict__ B,
                                         float* __restrict__ out)
{
    #pragma unroll
    for (int o4 = 0; o4 < O / 4; ++o4) {
        float a0 = B[o4 * 4 + 0], a1 = B[o4 * 4 + 1];
        float a2 = B[o4 * 4 + 2], a3 = B[o4 * 4 + 3];
        #pragma unroll
        for (int k = 0; k < K; ++k) {
            float4 wv = *reinterpret_cast<const float4*>(&W[k * O + o4 * 4]);
            float hv = v[k];
            a0 = fmaf(hv, wv.x, a0);
            a1 = fmaf(hv, wv.y, a1);
            a2 = fmaf(hv, wv.z, a2);
            a3 = fmaf(hv, wv.w, a3);
        }
        out[o4 * 4 + 0] = a0; out[o4 * 4 + 1] = a1;
        out[o4 * 4 + 2] = a2; out[o4 * 4 + 3] = a3;
    }
}

// ---------------------------------------------------------------------------
// k2 (r12 verbatim): encoders -> v40 LDS; comb + Q/K/V/skip MFMAs.
// ---------------------------------------------------------------------------
__global__ __launch_bounds__(256) void k2_enc(
    const float* __restrict__ h1pre,
    const float* __restrict__ node_interval, const float* __restrict__ node_degree,
    const float* __restrict__ Wtf, const float* __restrict__ btf,
    const float* __restrict__ Wd,  const float* __restrict__ bd,
    const float* __restrict__ Wenc, const float* __restrict__ benc,
    const float* __restrict__ Wx,  const float* __restrict__ bx,
    const float* __restrict__ Wcomb, const float* __restrict__ bcomb,
    const float* __restrict__ Wq,  const float* __restrict__ bq,
    const float* __restrict__ Wk,  const float* __restrict__ bk,
    const float* __restrict__ Wv,  const float* __restrict__ bv,
    const float* __restrict__ Wskip, const float* __restrict__ bskip,
    uint32_t* __restrict__ q32, uint32_t* __restrict__ kv32,
    float* __restrict__ skipb, int n)
{
    __shared__ __align__(16) float sWenc[64], sWx[256];
    __shared__ float sWtf[8], sbtf[8], sWd[8], sbd[8], sbenc[8], sbx[8];
    __shared__ __align__(16) _Float16 v40s[256][72];
    __shared__ __align__(16) _Float16 h1s[256][40];

    const int t = threadIdx.x;
    if (t < 8) {
        sWtf[t] = Wtf[t]; sbtf[t] = btf[t];
        sWd[t]  = Wd[t];  sbd[t]  = bd[t];
        sbenc[t] = benc[t]; sbx[t] = bx[t];
    }
    if (t < 64) sWenc[t] = Wenc[t];
    if (t < 256) sWx[t] = Wx[t];

    const int nid = blockIdx.x * 256 + t;
    const bool active = nid < n;

    __syncthreads();

    if (active) {
        float h1p[32];
        const float2* hp = reinterpret_cast<const float2*>(h1pre + (size_t)nid * 32);
        #pragma unroll
        for (int i = 0; i < 16; ++i) {
            float2 v2 = hp[i];
            h1p[2 * i] = v2.x; h1p[2 * i + 1] = v2.y;
        }
        const float ti = node_interval[nid], dg = node_degree[nid];
        float tf[8], de[8];
        #pragma unroll
        for (int j = 0; j < 8; ++j) {
            tf[j] = fmaf(ti, sWtf[j], sbtf[j]);
            de[j] = fmaf(dg, sWd[j], sbd[j]);
        }
        float xp[8];
        matvecKO<32, 8>(h1p, sWx, sbx, xp);
        #pragma unroll
        for (int o = 0; o < 8; ++o) xp[o] = tanhf(xp[o]);

        float ep0[8], ep1[8];
        matvecKO<8, 8>(tf, sWenc, sbenc, ep0);
        matvecKO<8, 8>(de, sWenc, sbenc, ep1);
        float sc0 = 0.f, sc1 = 0.f;
        #pragma unroll
        for (int o = 0; o < 8; ++o) {
            sc0 = fmaf(tanhf(ep0[o]), xp[o], sc0);
            sc1 = fmaf(tanhf(ep1[o]), xp[o], sc1);
        }
        const float mm = fmaxf(sc0, sc1);
        const float e0 = __expf(sc0 - mm), e1 = __expf(sc1 - mm);
        const float inv = 1.f / (e0 + e1);
        const float s0 = e0 * inv, s1 = e1 * inv;

        #pragma unroll
        for (int i = 0; i < 32; ++i) v40s[t][i] = (_Float16)h1p[i];
        #pragma unroll
        for (int j = 0; j < 8; ++j)
            v40s[t][32 + j] = (_Float16)fmaf(s0, tf[j], s1 * de[j]);
    } else {
        #pragma unroll
        for (int i = 0; i < 40; ++i) v40s[t][i] = (_Float16)0.f;
    }
    #pragma unroll
    for (int i = 40; i < 64; ++i) v40s[t][i] = (_Float16)0.f;

    __syncthreads();

    const int lane = t & 63;
    const int g = lane >> 4, m = lane & 15;
    const int wv = t >> 6;
    const int node0 = blockIdx.x * 256;

    f16x8 Bc0[2], Bc1[2];
    #pragma unroll
    for (int s = 0; s < 2; ++s)
        #pragma unroll
        for (int i = 0; i < 8; ++i) {
            const int k = s * 32 + g * 8 + i;
            Bc0[s][i] = (_Float16)((k < 40) ? Wcomb[k * 32 + m] : 0.f);
            Bc1[s][i] = (_Float16)((k < 40) ? Wcomb[k * 32 + 16 + m] : 0.f);
        }
    const float bc0 = bcomb[m], bc1 = bcomb[16 + m];

    for (int c = wv; c < 16; c += 4) {
        f32x4 a0 = {0.f, 0.f, 0.f, 0.f};
        f32x4 a1 = {0.f, 0.f, 0.f, 0.f};
        #pragma unroll
        for (int s = 0; s < 2; ++s) {
            const f16x8 A = *reinterpret_cast<const f16x8*>(&v40s[c * 16 + m][s * 32 + g * 8]);
            a0 = __builtin_amdgcn_mfma_f32_16x16x32_f16(A, Bc0[s], a0, 0, 0, 0);
            a1 = __builtin_amdgcn_mfma_f32_16x16x32_f16(A, Bc1[s], a1, 0, 0, 0);
        }
        #pragma unroll
        for (int r = 0; r < 4; ++r) {
            const int nb = c * 16 + 4 * g + r;
            h1s[nb][m]      = (_Float16)(a0[r] + bc0);
            h1s[nb][16 + m] = (_Float16)(a1[r] + bc1);
        }
    }
    __syncthreads();

    f16x8 Bq0, Bq1, Bk0, Bk1, Bv0, Bv1, Bs0, Bs1;
    #pragma unroll
    for (int i = 0; i < 8; ++i) {
        const int k = g * 8 + i;
        Bq0[i] = (_Float16)Wq[k * 32 + m];     Bq1[i] = (_Float16)Wq[k * 32 + 16 + m];
        Bk0[i] = (_Float16)Wk[k * 32 + m];     Bk1[i] = (_Float16)Wk[k * 32 + 16 + m];
        Bv0[i] = (_Float16)Wv[k * 32 + m];     Bv1[i] = (_Float16)Wv[k * 32 + 16 + m];
        Bs0[i] = (_Float16)Wskip[k * 32 + m];  Bs1[i] = (_Float16)Wskip[k * 32 + 16 + m];
    }
    const float bq0 = bq[m], bq1 = bq[16 + m];
    const float bk0 = bk[m], bk1 = bk[16 + m];
    const float bv0 = bv[m], bv1 = bv[16 + m];
    const float bs0 = bskip[m], bs1 = bskip[16 + m];

    for (int c = wv; c < 16; c += 4) {
        const f16x8 A = *reinterpret_cast<const f16x8*>(&h1s[c * 16 + m][g * 8]);

        f32x4 aq0 = {0.f,0.f,0.f,0.f}, aq1 = {0.f,0.f,0.f,0.f};
        f32x4 ak0 = {0.f,0.f,0.f,0.f}, ak1 = {0.f,0.f,0.f,0.f};
        f32x4 av0 = {0.f,0.f,0.f,0.f}, av1 = {0.f,0.f,0.f,0.f};
        f32x4 as0 = {0.f,0.f,0.f,0.f}, as1 = {0.f,0.f,0.f,0.f};
        aq0 = __builtin_amdgcn_mfma_f32_16x16x32_f16(A, Bq0, aq0, 0, 0, 0);
        aq1 = __builtin_amdgcn_mfma_f32_16x16x32_f16(A, Bq1, aq1, 0, 0, 0);
        ak0 = __builtin_amdgcn_mfma_f32_16x16x32_f16(A, Bk0, ak0, 0, 0, 0);
        ak1 = __builtin_amdgcn_mfma_f32_16x16x32_f16(A, Bk1, ak1, 0, 0, 0);
        av0 = __builtin_amdgcn_mfma_f32_16x16x32_f16(A, Bv0, av0, 0, 0, 0);
        av1 = __builtin_amdgcn_mfma_f32_16x16x32_f16(A, Bv1, av1, 0, 0, 0);
        as0 = __builtin_amdgcn_mfma_f32_16x16x32_f16(A, Bs0, as0, 0, 0, 0);
        as1 = __builtin_amdgcn_mfma_f32_16x16x32_f16(A, Bs1, as1, 0, 0, 0);

        #pragma unroll
        for (int r = 0; r < 4; ++r) {
            const int node = node0 + c * 16 + 4 * g + r;
            if (node < n) {
                q32[(size_t)node * 16 + m] =
                    cvt_pk_bf16(aq0[r] + bq0, aq1[r] + bq1);
                uint2 kvd;
                kvd.x = cvt_pk_bf16(ak0[r] + bk0, ak1[r] + bk1);
                kvd.y = cvt_pk_bf16(av0[r] + bv0, av1[r] + bv1);
                *reinterpret_cast<uint2*>(kv32 + (size_t)node * 32 + 2 * m) = kvd;
                skipb[(size_t)node * 32 + m]      = as0[r] + bs0;
                skipb[(size_t)node * 32 + 16 + m] = as1[r] + bs1;
            }
        }
    }
}

// ---------------------------------------------------------------------------
// pass A: per-bucket counts.
// ---------------------------------------------------------------------------
__global__ __launch_bounds__(256) void kA_count(
    const int* __restrict__ ei, int* __restrict__ cnt, int numE, int B)
{
    __shared__ int hist[784];
    const int t = threadIdx.x;
    for (int i = t; i < B; i += 256) hist[i] = 0;
    __syncthreads();

    const int stride = gridDim.x * 256;
    for (int e = blockIdx.x * 256 + t; e < numE; e += stride)
        atomicAdd(&hist[ei[numE + e] >> 7], 1);
    __syncthreads();

    for (int i = t; i < B; i += 256)
        if (hist[i]) atomicAdd(&cnt[i], hist[i]);
}

// ---------------------------------------------------------------------------
// pass B: exclusive scan of cnt (B <= 1024) -> rowptr[B+1], cursor.
// ---------------------------------------------------------------------------
__global__ __launch_bounds__(1024) void kB_scan(
    const int* __restrict__ cnt, int* __restrict__ rowptr,
    int* __restrict__ cursor, int B)
{
    __shared__ int sh[1024];
    const int t = threadIdx.x;
    const int v = (t < B) ? cnt[t] : 0;
    sh[t] = v; __syncthreads();
    for (int off = 1; off < 1024; off <<= 1) {
        int add = (t >= off) ? sh[t - off] : 0;
        __syncthreads();
        sh[t] += add;
        __syncthreads();
    }
    if (t < B) {
        const int excl = sh[t] - v;
        rowptr[t] = excl;
        cursor[t] = excl;
        if (t == B - 1) rowptr[B] = sh[t];
    }
}

// ---------------------------------------------------------------------------
// pass C: scatter payload {src, rel_f16|dstlow<<16} into bucket regions.
// One block per CHUNK of 8192 edges; LDS bucketing gives ~10-edge runs per
// (chunk,bucket) -> line-efficient writes.
// pair pack: p(13b) | dstlow(7b)<<13 | b(10b)<<20
// ---------------------------------------------------------------------------
__global__ __launch_bounds__(256) void kC_scatter(
    const int* __restrict__ ei, const float* __restrict__ node_time,
    const float* __restrict__ edge_time, int* __restrict__ cursor,
    uint2* __restrict__ payload, int numE, int B)
{
    __shared__ uint32_t pairs[CHUNK];
    __shared__ int hist[784];
    __shared__ int base[784];

    const int t = threadIdx.x;
    const int e0 = blockIdx.x * CHUNK;
    const int cntC = min(CHUNK, numE - e0);

    for (int i = t; i < B; i += 256) hist[i] = 0;
    __syncthreads();

    // phase 1: bucket + local position
    #pragma unroll
    for (int i = 0; i < CHUNK / 256; ++i) {
        const int slot = i * 256 + t;
        if (slot < cntC) {
            const int dst = ei[numE + e0 + slot];
            const int b = dst >> 7;
            const int p = atomicAdd(&hist[b], 1);
            pairs[slot] = (uint32_t)p | ((uint32_t)(dst & 127) << 13)
                                      | ((uint32_t)b << 20);
        }
    }
    __syncthreads();

    // phase 2: reserve global ranges
    for (int j = t; j < B; j += 256)
        base[j] = hist[j] ? atomicAdd(&cursor[j], hist[j]) : 0;
    __syncthreads();

    // phase 3: write payloads
    #pragma unroll
    for (int i = 0; i < CHUNK / 256; ++i) {
        const int slot = i * 256 + t;
        if (slot < cntC) {
            const uint32_t pr = pairs[slot];
            const int p  = pr & 0x1FFF;
            const int dl = (pr >> 13) & 127;
            const int b  = pr >> 20;
            const int e  = e0 + slot;
            const int src = ei[e];
            const float rel = node_time[src] - edge_time[e];
            union { _Float16 h; unsigned short s; } rb;
            rb.h = (_Float16)rel;
            uint2 pl;
            pl.x = (uint32_t)src;
            pl.y = (uint32_t)rb.s | ((uint32_t)dl << 16);
            payload[base[b] + p] = pl;
        }
    }
}

// ---------------------------------------------------------------------------
// k3b: one block per bucket (128 dst nodes). q in LDS; kv gathered (bf16
// quads, r12 pattern); MFMA edge features; attention; fp32 LDS aggregation
// (ds_add_f32, rows padded to 33 to break group bank collisions); fused
// epilogue: h2 = agg/den + skip -> @Wout -> log_softmax -> 8B/node.
// ---------------------------------------------------------------------------
__global__ __launch_bounds__(256) void k3_bucket(
    const uint2* __restrict__ payload, const int* __restrict__ rowptr,
    const uint32_t* __restrict__ qp, const uint32_t* __restrict__ kvp,
    const float* __restrict__ Wt, const float* __restrict__ bt,
    const float* __restrict__ We, const float* __restrict__ be,
    const float* __restrict__ skipb,
    const float* __restrict__ Wout, const float* __restrict__ bout,
    float* __restrict__ out, int n)
{
    __shared__ uint32_t qlds[128 * 16];        // 8 KB
    __shared__ float agg[128 * 33];            // 16.9 KB (padded rows)
    __shared__ float den[256];                 // 1 KB
    __shared__ float sW[64];
    __shared__ float sb2[2];

    const int t = threadIdx.x;
    const int bkt = blockIdx.x;
    const int node0 = bkt << 7;
    const int beg = rowptr[bkt], end = rowptr[bkt + 1];

    // init LDS
    #pragma unroll
    for (int i = 0; i < 8; ++i) {
        const int idx = i * 256 + t;           // 2048 q words
        const int node = node0 + (idx >> 4);
        qlds[idx] = (node < n) ? qp[(size_t)node * 16 + (idx & 15)] : 0u;
    }
    for (int i = t; i < 128 * 33; i += 256) agg[i] = 0.f;
    if (t < 256) den[t] = 0.f;
    if (t < 64) sW[t] = Wout[t];
    if (t < 2)  sb2[t] = bout[t];

    const int lane = t & 63;
    const int g = lane >> 4, m = lane & 15;
    const int w = t >> 6;

    float wtr[8], btr[8];
    f16x8 B0f, B1f;
    #pragma unroll
    for (int i = 0; i < 8; ++i) {
        const int k = g * 8 + i;
        wtr[i] = Wt[k]; btr[i] = bt[k];
        B0f[i] = (_Float16)We[k * 32 + m];
        B1f[i] = (_Float16)We[k * 32 + 16 + m];
    }
    const float be0 = be[m], be1 = be[16 + m];

    __syncthreads();

    const int nEdges = end - beg;
    for (int t16 = w * 16; t16 < nEdges; t16 += 64) {
        // payload for edge t16+m (coalesced 8B)
        const int eA = beg + t16 + m;
        uint2 pl = make_uint2(0u, 0u);
        if (eA < end) pl = payload[eA];
        const int srcm = (int)pl.x;
        const int dlm  = (pl.y >> 16) & 127;
        union { unsigned short s; _Float16 h; } rb;
        rb.s = (unsigned short)(pl.y & 0xFFFF);
        const float rel = (float)rb.h;

        // gathers for my group's 4 edges (issued before compute)
        int dlr[4]; uint2 kvw[4]; uint32_t qw[4];
        #pragma unroll
        for (int r = 0; r < 4; ++r) {
            const int j = g * 4 + r;
            const int s_ = __shfl(srcm, j);
            dlr[r] = __shfl(dlm, j);
            kvw[r] = *reinterpret_cast<const uint2*>(kvp + (size_t)s_ * 32 + 2 * m);
            qw[r]  = qlds[dlr[r] * 16 + m];
        }

        // edge features: cos + 2x MFMA (overlaps the kv gathers)
        f16x8 A;
        #pragma unroll
        for (int i = 0; i < 8; ++i)
            A[i] = (_Float16)__cosf(fmaf(rel, wtr[i], btr[i]));

        f32x4 acc0 = {0.f, 0.f, 0.f, 0.f};
        f32x4 acc1 = {0.f, 0.f, 0.f, 0.f};
        acc0 = __builtin_amdgcn_mfma_f32_16x16x32_f16(A, B0f, acc0, 0, 0, 0);
        acc1 = __builtin_amdgcn_mfma_f32_16x16x32_f16(A, B1f, acc1, 0, 0, 0);

        #pragma unroll
        for (int r = 0; r < 4; ++r) {
            if (t16 + g * 4 + r < nEdges) {
                const float ef0 = acc0[r] + be0;
                const float ef1 = acc1[r] + be1;
                const uint32_t uq = qw[r], uk = kvw[r].x, uv = kvw[r].y;

                float p0 = bflo(uq) * (bflo(uk) + ef0);
                float p1 = bfhi(uq) * (bfhi(uk) + ef1);
                #pragma unroll
                for (int s = 1; s < 16; s <<= 1) {
                    p0 += __shfl_xor(p0, s);
                    p1 += __shfl_xor(p1, s);
                }
                const float w0 = __expf(p0 * INV_SQRT_C);
                const float w1 = __expf(p1 * INV_SQRT_C);

                const float t0 = w0 * (bflo(uv) + ef0);
                const float t1 = w1 * (bfhi(uv) + ef1);

                atomicAdd(&agg[dlr[r] * 33 + m],      t0);
                atomicAdd(&agg[dlr[r] * 33 + 16 + m], t1);
                if (m == 0) {
                    atomicAdd(&den[dlr[r] * 2],     w0);
                    atomicAdd(&den[dlr[r] * 2 + 1], w1);
                }
            }
        }
    }
    __syncthreads();

    // fused epilogue: one thread per node
    if (t < 128) {
        const int node = node0 + t;
        if (node < n) {
            const float inv0 = 1.f / (den[t * 2]     + 1e-16f);
            const float inv1 = 1.f / (den[t * 2 + 1] + 1e-16f);
            const float* sk = skipb + (size_t)node * 32;
            float o0 = sb2[0], o1 = sb2[1];
            #pragma unroll
            for (int c = 0; c < 32; ++c) {
                const float iv = (c < 16) ? inv0 : inv1;
                const float h = fmaf(agg[t * 33 + c], iv, sk[c]);
                o0 = fmaf(h, sW[c * 2],     o0);
                o1 = fmaf(h, sW[c * 2 + 1], o1);
            }
            const float mm = fmaxf(o0, o1);
            const float lse = mm + __logf(__expf(o0 - mm) + __expf(o1 - mm));
            out[(size_t)node * 2 + 0] = o0 - lse;
            out[(size_t)node * 2 + 1] = o1 - lse;
        }
    }
}

// ---------------------------------------------------------------------------
extern "C" void kernel_launch(void* const* d_in, const int* in_sizes, int n_in,
                              void* d_out, int out_size, void* d_ws, size_t ws_size,
                              hipStream_t stream)
{
    const float* x             = (const float*)d_in[0];
    const int*   ei            = (const int*)  d_in[1];
    const float* node_time     = (const float*)d_in[2];
    const float* edge_time     = (const float*)d_in[3];
    const float* node_interval = (const float*)d_in[4];
    const float* node_degree   = (const float*)d_in[5];
    const float* Wt    = (const float*)d_in[6];  const float* bt    = (const float*)d_in[7];
    const float* Wd    = (const float*)d_in[8];  const float* bd    = (const float*)d_in[9];
    const float* Wtf   = (const float*)d_in[10]; const float* btf   = (const float*)d_in[11];
    const float* Wenc  = (const float*)d_in[12]; const float* benc  = (const float*)d_in[13];
    const float* Wx    = (const float*)d_in[14]; const float* bx    = (const float*)d_in[15];
    const float* Wlin  = (const float*)d_in[16]; const float* blin  = (const float*)d_in[17];
    const float* Wcomb = (const float*)d_in[18]; const float* bcomb = (const float*)d_in[19];
    const float* Wq    = (const float*)d_in[20]; const float* bq    = (const float*)d_in[21];
    const float* Wk    = (const float*)d_in[22]; const float* bk    = (const float*)d_in[23];
    const float* Wv    = (const float*)d_in[24]; const float* bv    = (const float*)d_in[25];
    const float* We    = (const float*)d_in[26]; const float* be    = (const float*)d_in[27];
    const float* Wskip = (const float*)d_in[28]; const float* bskip = (const float*)d_in[29];
    const float* Wout  = (const float*)d_in[30]; const float* bout  = (const float*)d_in[31];

    const int n    = in_sizes[2];   // node_time: [N]
    const int numE = in_sizes[3];   // edge_time: [E,1]
    const int B    = (n + 127) >> 7;            // buckets (<=784 for n<=100352)

    // ---- workspace carve (bytes) ----
    char* base = (char*)d_ws;
    uint32_t* q32  = (uint32_t*)base; base += (size_t)n * 16 * 4;
    uint32_t* kv32 = (uint32_t*)base; base += (size_t)n * 32 * 4;
    float* skipb = (float*)base; base += (size_t)n * 32 * 4;
    float* h1pre = (float*)base; base += (size_t)n * 32 * 4;
    uint2* payload = (uint2*)base; base += (size_t)numE * 8;
    int* rowptr = (int*)base; base += (size_t)(B + 1) * 4;
    int* cnt    = (int*)base; base += (size_t)B * 4;
    int* cursor = (int*)base; base += (size_t)B * 4;

    hipMemsetAsync(cnt, 0, (size_t)B * 4, stream);

    kA_count<<<1024, 256, 0, stream>>>(ei, cnt, numE, B);
    kB_scan<<<1, 1024, 0, stream>>>(cnt, rowptr, cursor, B);

    const int nChunks = (numE + CHUNK - 1) / CHUNK;
    kC_scatter<<<nChunks, 256, 0, stream>>>(
        ei, node_time, edge_time, cursor, payload, numE, B);

    k1_lin<<<512, 256, 0, stream>>>(x, Wlin, blin, h1pre, n);

    k2_enc<<<(n + 255) / 256, 256, 0, stream>>>(
        h1pre, node_interval, node_degree,
        Wtf, btf, Wd, bd, Wenc, benc, Wx, bx, Wcomb, bcomb,
        Wq, bq, Wk, bk, Wv, bv, Wskip, bskip,
        q32, kv32, skipb, n);

    k3_bucket<<<B, 256, 0, stream>>>(
        payload, rowptr, q32, kv32, Wt, bt, We, be,
        skipb, Wout, bout, (float*)d_out, n);
}

// Round 15
// 409.655 us; speedup vs baseline: 2.4490x; 2.4490x over previous
//
#include <hip/hip_runtime.h>
#include <hip/hip_bf16.h>
#include <cstdint>

// TGAT fused pipeline for MI355X — round 14: depth-2 gather pipeline on the
// r12 optimum. Each tile's q/kv/node_time gathers are issued TWO compute
// phases before use (r12: one); two gather sets ping-pong in registers;
// atomics issued last, never on a wait path.
// Stages: k1 MFMA lin | k2 MFMA enc/proj | k3 edge (depth-2) | k4 epilogue

#define FIN 172
#define INV_SQRT_C 0.25f

typedef _Float16 f16x8 __attribute__((ext_vector_type(8)));
typedef float f32x4 __attribute__((ext_vector_type(4)));
typedef short s16x2 __attribute__((ext_vector_type(2)));

__device__ __forceinline__ uint32_t cvt_pk_bf16(float lo, float hi) {
    uint32_t r;
    asm("v_cvt_pk_bf16_f32 %0, %1, %2" : "=v"(r) : "v"(lo), "v"(hi));
    return r;
}
__device__ __forceinline__ float bflo(uint32_t u) {
    union { uint32_t i; float f; } x; x.i = u << 16; return x.f;
}
__device__ __forceinline__ float bfhi(uint32_t u) {
    union { uint32_t i; float f; } x; x.i = u & 0xFFFF0000u; return x.f;
}
__device__ __forceinline__ void pk_atomic_add_bf16(void* addr, uint32_t data) {
#if __has_builtin(__builtin_amdgcn_global_atomic_fadd_v2bf16)
    typedef __attribute__((address_space(1))) s16x2* gp1;
    union { uint32_t u; s16x2 v; } c; c.u = data;
    __builtin_amdgcn_global_atomic_fadd_v2bf16((gp1)(uintptr_t)addr, c.v);
#else
    asm volatile("global_atomic_pk_add_bf16 %0, %1, off"
                 :: "v"((uint64_t)(uintptr_t)addr), "v"(data));
#endif
}

// ---------------------------------------------------------------------------
// k1 (MFMA): h1pre = x @ Wlin + blin.  (r12 verbatim)
// ---------------------------------------------------------------------------
__global__ __launch_bounds__(256) void k1_lin(
    const float* __restrict__ x, const float* __restrict__ Wlin,
    const float* __restrict__ blin, float* __restrict__ h1pre, int n)
{
    const int lane = threadIdx.x & 63;
    const int g = lane >> 4, m = lane & 15;

    f16x8 Bf[6][2];
    #pragma unroll
    for (int s = 0; s < 6; ++s) {
        #pragma unroll
        for (int i = 0; i < 8; ++i) {
            const int k = s * 32 + g * 8 + i;
            Bf[s][0][i] = (_Float16)((k < FIN) ? Wlin[k * 32 + m] : 0.f);
            Bf[s][1][i] = (_Float16)((k < FIN) ? Wlin[k * 32 + 16 + m] : 0.f);
        }
    }
    const float b0 = blin[m], b1 = blin[16 + m];

    const int wid = blockIdx.x * 4 + (threadIdx.x >> 6);
    const int nW  = gridDim.x * 4;
    const int nChunks = (n + 15) / 16;

    for (int c = wid; c < nChunks; c += nW) {
        const int row = c * 16 + m;
        const bool rv = row < n;
        const float* xr = x + (size_t)row * FIN;

        f32x4 acc0 = {0.f, 0.f, 0.f, 0.f};
        f32x4 acc1 = {0.f, 0.f, 0.f, 0.f};
        #pragma unroll
        for (int s = 0; s < 6; ++s) {
            f16x8 A;
            #pragma unroll
            for (int i = 0; i < 8; ++i) {
                const int k = s * 32 + g * 8 + i;
                A[i] = (_Float16)((rv && k < FIN) ? xr[k] : 0.f);
            }
            acc0 = __builtin_amdgcn_mfma_f32_16x16x32_f16(A, Bf[s][0], acc0, 0, 0, 0);
            acc1 = __builtin_amdgcn_mfma_f32_16x16x32_f16(A, Bf[s][1], acc1, 0, 0, 0);
        }
        #pragma unroll
        for (int r = 0; r < 4; ++r) {
            const int node = c * 16 + 4 * g + r;
            if (node < n) {
                h1pre[(size_t)node * 32 + m]      = acc0[r] + b0;
                h1pre[(size_t)node * 32 + 16 + m] = acc1[r] + b1;
            }
        }
    }
}

// ---------------------------------------------------------------------------
template <int K, int O>
__device__ __forceinline__ void matvecKO(const float* __restrict__ v,
                                         const float* __restrict__ W,
                                         const float* __restrict__ B,
                                         float* __restrict__ out)
{
    #pragma unroll
    for (int o4 = 0; o4 < O / 4; ++o4) {
        float a0 = B[o4 * 4 + 0], a1 = B[o4 * 4 + 1];
        float a2 = B[o4 * 4 + 2], a3 = B[o4 * 4 + 3];
        #pragma unroll
        for (int k = 0; k < K; ++k) {
            float4 wv = *reinterpret_cast<const float4*>(&W[k * O + o4 * 4]);
            float hv = v[k];
            a0 = fmaf(hv, wv.x, a0);
            a1 = fmaf(hv, wv.y, a1);
            a2 = fmaf(hv, wv.z, a2);
            a3 = fmaf(hv, wv.w, a3);
        }
        out[o4 * 4 + 0] = a0; out[o4 * 4 + 1] = a1;
        out[o4 * 4 + 2] = a2; out[o4 * 4 + 3] = a3;
    }
}

// ---------------------------------------------------------------------------
// k2 (r12 verbatim): encoders -> v40 LDS; comb + Q/K/V/skip MFMAs.
// ---------------------------------------------------------------------------
__global__ __launch_bounds__(256) void k2_enc(
    const float* __restrict__ h1pre,
    const float* __restrict__ node_interval, const float* __restrict__ node_degree,
    const float* __restrict__ Wtf, const float* __restrict__ btf,
    const float* __restrict__ Wd,  const float* __restrict__ bd,
    const float* __restrict__ Wenc, const float* __restrict__ benc,
    const float* __restrict__ Wx,  const float* __restrict__ bx,
    const float* __restrict__ Wcomb, const float* __restrict__ bcomb,
    const float* __restrict__ Wq,  const float* __restrict__ bq,
    const float* __restrict__ Wk,  const float* __restrict__ bk,
    const float* __restrict__ Wv,  const float* __restrict__ bv,
    const float* __restrict__ Wskip, const float* __restrict__ bskip,
    uint32_t* __restrict__ q32, uint32_t* __restrict__ kv32,
    float* __restrict__ skipb, int n)
{
    __shared__ __align__(16) float sWenc[64], sWx[256];
    __shared__ float sWtf[8], sbtf[8], sWd[8], sbd[8], sbenc[8], sbx[8];
    __shared__ __align__(16) _Float16 v40s[256][72];
    __shared__ __align__(16) _Float16 h1s[256][40];

    const int t = threadIdx.x;
    if (t < 8) {
        sWtf[t] = Wtf[t]; sbtf[t] = btf[t];
        sWd[t]  = Wd[t];  sbd[t]  = bd[t];
        sbenc[t] = benc[t]; sbx[t] = bx[t];
    }
    if (t < 64) sWenc[t] = Wenc[t];
    if (t < 256) sWx[t] = Wx[t];

    const int nid = blockIdx.x * 256 + t;
    const bool active = nid < n;

    __syncthreads();

    if (active) {
        float h1p[32];
        const float2* hp = reinterpret_cast<const float2*>(h1pre + (size_t)nid * 32);
        #pragma unroll
        for (int i = 0; i < 16; ++i) {
            float2 v2 = hp[i];
            h1p[2 * i] = v2.x; h1p[2 * i + 1] = v2.y;
        }
        const float ti = node_interval[nid], dg = node_degree[nid];
        float tf[8], de[8];
        #pragma unroll
        for (int j = 0; j < 8; ++j) {
            tf[j] = fmaf(ti, sWtf[j], sbtf[j]);
            de[j] = fmaf(dg, sWd[j], sbd[j]);
        }
        float xp[8];
        matvecKO<32, 8>(h1p, sWx, sbx, xp);
        #pragma unroll
        for (int o = 0; o < 8; ++o) xp[o] = tanhf(xp[o]);

        float ep0[8], ep1[8];
        matvecKO<8, 8>(tf, sWenc, sbenc, ep0);
        matvecKO<8, 8>(de, sWenc, sbenc, ep1);
        float sc0 = 0.f, sc1 = 0.f;
        #pragma unroll
        for (int o = 0; o < 8; ++o) {
            sc0 = fmaf(tanhf(ep0[o]), xp[o], sc0);
            sc1 = fmaf(tanhf(ep1[o]), xp[o], sc1);
        }
        const float mm = fmaxf(sc0, sc1);
        const float e0 = __expf(sc0 - mm), e1 = __expf(sc1 - mm);
        const float inv = 1.f / (e0 + e1);
        const float s0 = e0 * inv, s1 = e1 * inv;

        #pragma unroll
        for (int i = 0; i < 32; ++i) v40s[t][i] = (_Float16)h1p[i];
        #pragma unroll
        for (int j = 0; j < 8; ++j)
            v40s[t][32 + j] = (_Float16)fmaf(s0, tf[j], s1 * de[j]);
    } else {
        #pragma unroll
        for (int i = 0; i < 40; ++i) v40s[t][i] = (_Float16)0.f;
    }
    #pragma unroll
    for (int i = 40; i < 64; ++i) v40s[t][i] = (_Float16)0.f;

    __syncthreads();

    const int lane = t & 63;
    const int g = lane >> 4, m = lane & 15;
    const int wv = t >> 6;
    const int node0 = blockIdx.x * 256;

    f16x8 Bc0[2], Bc1[2];
    #pragma unroll
    for (int s = 0; s < 2; ++s)
        #pragma unroll
        for (int i = 0; i < 8; ++i) {
            const int k = s * 32 + g * 8 + i;
            Bc0[s][i] = (_Float16)((k < 40) ? Wcomb[k * 32 + m] : 0.f);
            Bc1[s][i] = (_Float16)((k < 40) ? Wcomb[k * 32 + 16 + m] : 0.f);
        }
    const float bc0 = bcomb[m], bc1 = bcomb[16 + m];

    for (int c = wv; c < 16; c += 4) {
        f32x4 a0 = {0.f, 0.f, 0.f, 0.f};
        f32x4 a1 = {0.f, 0.f, 0.f, 0.f};
        #pragma unroll
        for (int s = 0; s < 2; ++s) {
            const f16x8 A = *reinterpret_cast<const f16x8*>(&v40s[c * 16 + m][s * 32 + g * 8]);
            a0 = __builtin_amdgcn_mfma_f32_16x16x32_f16(A, Bc0[s], a0, 0, 0, 0);
            a1 = __builtin_amdgcn_mfma_f32_16x16x32_f16(A, Bc1[s], a1, 0, 0, 0);
        }
        #pragma unroll
        for (int r = 0; r < 4; ++r) {
            const int nb = c * 16 + 4 * g + r;
            h1s[nb][m]      = (_Float16)(a0[r] + bc0);
            h1s[nb][16 + m] = (_Float16)(a1[r] + bc1);
        }
    }
    __syncthreads();

    f16x8 Bq0, Bq1, Bk0, Bk1, Bv0, Bv1, Bs0, Bs1;
    #pragma unroll
    for (int i = 0; i < 8; ++i) {
        const int k = g * 8 + i;
        Bq0[i] = (_Float16)Wq[k * 32 + m];     Bq1[i] = (_Float16)Wq[k * 32 + 16 + m];
        Bk0[i] = (_Float16)Wk[k * 32 + m];     Bk1[i] = (_Float16)Wk[k * 32 + 16 + m];
        Bv0[i] = (_Float16)Wv[k * 32 + m];     Bv1[i] = (_Float16)Wv[k * 32 + 16 + m];
        Bs0[i] = (_Float16)Wskip[k * 32 + m];  Bs1[i] = (_Float16)Wskip[k * 32 + 16 + m];
    }
    const float bq0 = bq[m], bq1 = bq[16 + m];
    const float bk0 = bk[m], bk1 = bk[16 + m];
    const float bv0 = bv[m], bv1 = bv[16 + m];
    const float bs0 = bskip[m], bs1 = bskip[16 + m];

    for (int c = wv; c < 16; c += 4) {
        const f16x8 A = *reinterpret_cast<const f16x8*>(&h1s[c * 16 + m][g * 8]);

        f32x4 aq0 = {0.f,0.f,0.f,0.f}, aq1 = {0.f,0.f,0.f,0.f};
        f32x4 ak0 = {0.f,0.f,0.f,0.f}, ak1 = {0.f,0.f,0.f,0.f};
        f32x4 av0 = {0.f,0.f,0.f,0.f}, av1 = {0.f,0.f,0.f,0.f};
        f32x4 as0 = {0.f,0.f,0.f,0.f}, as1 = {0.f,0.f,0.f,0.f};
        aq0 = __builtin_amdgcn_mfma_f32_16x16x32_f16(A, Bq0, aq0, 0, 0, 0);
        aq1 = __builtin_amdgcn_mfma_f32_16x16x32_f16(A, Bq1, aq1, 0, 0, 0);
        ak0 = __builtin_amdgcn_mfma_f32_16x16x32_f16(A, Bk0, ak0, 0, 0, 0);
        ak1 = __builtin_amdgcn_mfma_f32_16x16x32_f16(A, Bk1, ak1, 0, 0, 0);
        av0 = __builtin_amdgcn_mfma_f32_16x16x32_f16(A, Bv0, av0, 0, 0, 0);
        av1 = __builtin_amdgcn_mfma_f32_16x16x32_f16(A, Bv1, av1, 0, 0, 0);
        as0 = __builtin_amdgcn_mfma_f32_16x16x32_f16(A, Bs0, as0, 0, 0, 0);
        as1 = __builtin_amdgcn_mfma_f32_16x16x32_f16(A, Bs1, as1, 0, 0, 0);

        #pragma unroll
        for (int r = 0; r < 4; ++r) {
            const int node = node0 + c * 16 + 4 * g + r;
            if (node < n) {
                q32[(size_t)node * 16 + m] =
                    cvt_pk_bf16(aq0[r] + bq0, aq1[r] + bq1);
                uint2 kvd;
                kvd.x = cvt_pk_bf16(ak0[r] + bk0, ak1[r] + bk1);
                kvd.y = cvt_pk_bf16(av0[r] + bv0, av1[r] + bv1);
                *reinterpret_cast<uint2*>(kv32 + (size_t)node * 32 + 2 * m) = kvd;
                skipb[(size_t)node * 32 + m]      = as0[r] + bs0;
                skipb[(size_t)node * 32 + 16 + m] = as1[r] + bs1;
            }
        }
    }
}

// ---------------------------------------------------------------------------
// k3: depth-2 gather pipeline. Two gather sets (A,B) ping-pong; tile t's
// gathers are issued two compute phases before use. Atomics last.
// ---------------------------------------------------------------------------
struct GatherSet {
    float nt, et;
    int   e0;            // numE when tile invalid (disables all edges)
    int   dstr[4];
    uint32_t qw[4];
    uint2 kvw[4];
};

__device__ __forceinline__ void stage1(
    const int* __restrict__ ei, const float* __restrict__ edge_time,
    int numE, int nTiles, int tile, int m,
    int& src, int& dst, float& et)
{
    src = 0; dst = 0; et = 0.f;
    if (tile < nTiles) {
        const int eA = tile * 16 + m;
        if (eA < numE) { src = ei[eA]; dst = ei[numE + eA]; et = edge_time[eA]; }
    }
}

__device__ __forceinline__ void issue_gathers(
    const uint32_t* __restrict__ qp, const uint32_t* __restrict__ kvp,
    const float* __restrict__ node_time,
    int g, int m, int numE, int nTiles, int tile,
    int srcS, int dstS, float etS, GatherSet& G)
{
    G.nt = node_time[srcS];
    G.et = etS;
    G.e0 = (tile < nTiles) ? tile * 16 : numE;
    #pragma unroll
    for (int r = 0; r < 4; ++r) {
        const int j = g * 4 + r;
        const int s_ = __shfl(srcS, j);
        G.dstr[r] = __shfl(dstS, j);
        G.qw[r]  = qp[(size_t)G.dstr[r] * 16 + m];
        G.kvw[r] = *reinterpret_cast<const uint2*>(kvp + (size_t)s_ * 32 + 2 * m);
    }
}

__device__ __forceinline__ void compute_tile(
    const GatherSet& G, const float* wtr, const float* btr,
    const f16x8& B0, const f16x8& B1, float be0, float be1,
    int g, int m, int numE,
    uint32_t* outD, uint32_t* denD, int* outDst, bool* outV)
{
    const float rel = G.nt - G.et;
    f16x8 A;
    #pragma unroll
    for (int i = 0; i < 8; ++i)
        A[i] = (_Float16)__cosf(fmaf(rel, wtr[i], btr[i]));

    f32x4 acc0 = {0.f, 0.f, 0.f, 0.f};
    f32x4 acc1 = {0.f, 0.f, 0.f, 0.f};
    acc0 = __builtin_amdgcn_mfma_f32_16x16x32_f16(A, B0, acc0, 0, 0, 0);
    acc1 = __builtin_amdgcn_mfma_f32_16x16x32_f16(A, B1, acc1, 0, 0, 0);

    #pragma unroll
    for (int r = 0; r < 4; ++r) {
        outV[r]   = (G.e0 + g * 4 + r) < numE;
        outDst[r] = G.dstr[r];

        const float ef0 = acc0[r] + be0;
        const float ef1 = acc1[r] + be1;
        const uint32_t uq = G.qw[r], uk = G.kvw[r].x, uv = G.kvw[r].y;

        float p0 = bflo(uq) * (bflo(uk) + ef0);
        float p1 = bfhi(uq) * (bfhi(uk) + ef1);
        #pragma unroll
        for (int s = 1; s < 16; s <<= 1) {
            p0 += __shfl_xor(p0, s);
            p1 += __shfl_xor(p1, s);
        }
        const float w0 = __expf(p0 * INV_SQRT_C);
        const float w1 = __expf(p1 * INV_SQRT_C);

        const float t0 = w0 * (bflo(uv) + ef0);
        const float t1 = w1 * (bfhi(uv) + ef1);
        const float x0 = __shfl_xor(t0, 1);
        const float x1 = __shfl_xor(t1, 1);
        outD[r] = (m & 1) ? cvt_pk_bf16(x1, t1) : cvt_pk_bf16(t0, x0);
        denD[r] = cvt_pk_bf16(w0, w1);
    }
}

__device__ __forceinline__ void issue_atomics(
    unsigned short* __restrict__ agg, unsigned short* __restrict__ den,
    const uint32_t* outD, const uint32_t* denD,
    const int* outDst, const bool* outV, int m)
{
    const int choff = (m & 1) ? (15 + m) : m;
    #pragma unroll
    for (int r = 0; r < 4; ++r) {
        if (outV[r]) {
            pk_atomic_add_bf16(agg + (size_t)outDst[r] * 32 + choff, outD[r]);
            if (m == 0)
                pk_atomic_add_bf16(den + (size_t)outDst[r] * 32, denD[r]);
        }
    }
}

__global__ __launch_bounds__(256) void k3_edge(
    const int* __restrict__ ei, const float* __restrict__ node_time,
    const float* __restrict__ edge_time,
    const uint32_t* __restrict__ qp, const uint32_t* __restrict__ kvp,
    const float* __restrict__ Wt, const float* __restrict__ bt,
    const float* __restrict__ We, const float* __restrict__ be,
    unsigned short* __restrict__ agg, unsigned short* __restrict__ den,
    int numE, int nTiles)
{
    const int lane = threadIdx.x & 63;
    const int g = lane >> 4;
    const int m = lane & 15;

    float wtr[8], btr[8];
    f16x8 B0, B1;
    #pragma unroll
    for (int i = 0; i < 8; ++i) {
        const int k = g * 8 + i;
        wtr[i] = Wt[k];
        btr[i] = bt[k];
        B0[i] = (_Float16)We[k * 32 + m];
        B1[i] = (_Float16)We[k * 32 + 16 + m];
    }
    const float be0 = be[m], be1 = be[16 + m];

    const int wid = blockIdx.x * (blockDim.x >> 6) + (threadIdx.x >> 6);
    const int nW  = gridDim.x * (blockDim.x >> 6);

    int tile = wid;
    if (tile >= nTiles) return;

    // ---------------- prologue: fill both pipeline slots ----------------
    int srcA, dstA; float etA;
    int srcB, dstB; float etB;
    GatherSet GA, GB;

    stage1(ei, edge_time, numE, nTiles, tile, m, srcA, dstA, etA);
    issue_gathers(qp, kvp, node_time, g, m, numE, nTiles, tile, srcA, dstA, etA, GA);
    stage1(ei, edge_time, numE, nTiles, tile + 2 * nW, m, srcA, dstA, etA);

    stage1(ei, edge_time, numE, nTiles, tile + nW, m, srcB, dstB, etB);
    issue_gathers(qp, kvp, node_time, g, m, numE, nTiles, tile + nW, srcB, dstB, etB, GB);
    stage1(ei, edge_time, numE, nTiles, tile + 3 * nW, m, srcB, dstB, etB);

    uint32_t outD[4], denD[4];
    int outDst[4];
    bool outV[4];

    while (true) {
        // ---- slot A: compute tile, refill for tile+2nW, atomics ----
        compute_tile(GA, wtr, btr, B0, B1, be0, be1, g, m, numE,
                     outD, denD, outDst, outV);
        issue_gathers(qp, kvp, node_time, g, m, numE, nTiles, tile + 2 * nW,
                      srcA, dstA, etA, GA);
        stage1(ei, edge_time, numE, nTiles, tile + 4 * nW, m, srcA, dstA, etA);
        issue_atomics(agg, den, outD, denD, outDst, outV, m);

        if (tile + nW >= nTiles) break;

        // ---- slot B: compute tile+nW, refill for tile+3nW, atomics ----
        compute_tile(GB, wtr, btr, B0, B1, be0, be1, g, m, numE,
                     outD, denD, outDst, outV);
        issue_gathers(qp, kvp, node_time, g, m, numE, nTiles, tile + 3 * nW,
                      srcB, dstB, etB, GB);
        stage1(ei, edge_time, numE, nTiles, tile + 5 * nW, m, srcB, dstB, etB);
        issue_atomics(agg, den, outD, denD, outDst, outV, m);

        tile += 2 * nW;
        if (tile >= nTiles) break;
    }
}

// ---------------------------------------------------------------------------
// k4 (r12 verbatim): h2 = agg/den + skip; log_softmax(h2 @ Wout + bout).
// ---------------------------------------------------------------------------
__global__ __launch_bounds__(256) void k4_out(
    const unsigned short* __restrict__ agg, const unsigned short* __restrict__ den,
    const float* __restrict__ skipb,
    const float* __restrict__ Wout, const float* __restrict__ bout,
    float* __restrict__ out, int n)
{
    __shared__ float sW[64];
    __shared__ float sb[2];
    const int t = threadIdx.x;
    if (t < 64) sW[t] = Wout[t];
    if (t < 2) sb[t] = bout[t];
    __syncthreads();

    const int nid = blockIdx.x * 256 + t;
    if (nid >= n) return;

    const uint32_t ud = reinterpret_cast<const uint32_t*>(den)[(size_t)nid * 16];
    const float inv0 = 1.f / (bflo(ud) + 1e-16f);
    const float inv1 = 1.f / (bfhi(ud) + 1e-16f);
    const uint32_t* ag = reinterpret_cast<const uint32_t*>(agg) + (size_t)nid * 16;
    const float*    sk = skipb + (size_t)nid * 32;

    float o0 = sb[0], o1 = sb[1];
    #pragma unroll
    for (int p = 0; p < 16; ++p) {
        const uint32_t u = ag[p];
        const float iv = (p < 8) ? inv0 : inv1;
        const float hLo = fmaf(bflo(u), iv, sk[2 * p]);
        const float hHi = fmaf(bfhi(u), iv, sk[2 * p + 1]);
        o0 = fmaf(hLo, sW[(2 * p) * 2],     o0);
        o1 = fmaf(hLo, sW[(2 * p) * 2 + 1], o1);
        o0 = fmaf(hHi, sW[(2 * p + 1) * 2],     o0);
        o1 = fmaf(hHi, sW[(2 * p + 1) * 2 + 1], o1);
    }
    const float mm = fmaxf(o0, o1);
    const float lse = mm + __logf(__expf(o0 - mm) + __expf(o1 - mm));
    out[(size_t)nid * 2 + 0] = o0 - lse;
    out[(size_t)nid * 2 + 1] = o1 - lse;
}

// ---------------------------------------------------------------------------
extern "C" void kernel_launch(void* const* d_in, const int* in_sizes, int n_in,
                              void* d_out, int out_size, void* d_ws, size_t ws_size,
                              hipStream_t stream)
{
    const float* x             = (const float*)d_in[0];
    const int*   ei            = (const int*)  d_in[1];
    const float* node_time     = (const float*)d_in[2];
    const float* edge_time     = (const float*)d_in[3];
    const float* node_interval = (const float*)d_in[4];
    const float* node_degree   = (const float*)d_in[5];
    const float* Wt    = (const float*)d_in[6];  const float* bt    = (const float*)d_in[7];
    const float* Wd    = (const float*)d_in[8];  const float* bd    = (const float*)d_in[9];
    const float* Wtf   = (const float*)d_in[10]; const float* btf   = (const float*)d_in[11];
    const float* Wenc  = (const float*)d_in[12]; const float* benc  = (const float*)d_in[13];
    const float* Wx    = (const float*)d_in[14]; const float* bx    = (const float*)d_in[15];
    const float* Wlin  = (const float*)d_in[16]; const float* blin  = (const float*)d_in[17];
    const float* Wcomb = (const float*)d_in[18]; const float* bcomb = (const float*)d_in[19];
    const float* Wq    = (const float*)d_in[20]; const float* bq    = (const float*)d_in[21];
    const float* Wk    = (const float*)d_in[22]; const float* bk    = (const float*)d_in[23];
    const float* Wv    = (const float*)d_in[24]; const float* bv    = (const float*)d_in[25];
    const float* We    = (const float*)d_in[26]; const float* be    = (const float*)d_in[27];
    const float* Wskip = (const float*)d_in[28]; const float* bskip = (const float*)d_in[29];
    const float* Wout  = (const float*)d_in[30]; const float* bout  = (const float*)d_in[31];

    const int n    = in_sizes[2];   // node_time: [N]
    const int numE = in_sizes[3];   // edge_time: [E,1]

    // ---- workspace carve (bytes) ----
    char* base = (char*)d_ws;
    uint32_t* q32  = (uint32_t*)base; base += (size_t)n * 16 * 4;   // q pairs
    uint32_t* kv32 = (uint32_t*)base; base += (size_t)n * 32 * 4;   // kv quads
    float* skipb = (float*)base; base += (size_t)n * 32 * 4;
    float* h1pre = (float*)base; base += (size_t)n * 32 * 4;
    unsigned short* agg = (unsigned short*)base; base += (size_t)n * 32 * 2;
    unsigned short* den = (unsigned short*)base; base += (size_t)n * 32 * 2;

    // zero the atomic accumulators (agg + den rows, contiguous: 128 B/node)
    hipMemsetAsync(agg, 0, (size_t)n * 128, stream);

    k1_lin<<<512, 256, 0, stream>>>(x, Wlin, blin, h1pre, n);

    k2_enc<<<(n + 255) / 256, 256, 0, stream>>>(
        h1pre, node_interval, node_degree,
        Wtf, btf, Wd, bd, Wenc, benc, Wx, bx, Wcomb, bcomb,
        Wq, bq, Wk, bk, Wv, bv, Wskip, bskip,
        q32, kv32, skipb, n);

    const int nTiles = (numE + 15) / 16;
    k3_edge<<<4096, 256, 0, stream>>>(
        ei, node_time, edge_time, q32, kv32,
        Wt, bt, We, be, agg, den, numE, nTiles);

    k4_out<<<(n + 255) / 256, 256, 0, stream>>>(
        agg, den, skipb, Wout, bout, (float*)d_out, n);
}